// Round 4
// baseline (222.700 us; speedup 1.0000x reference)
//
#include <hip/hip_runtime.h>
#include <hip/hip_bf16.h>

#define NR 16384
#define CC 2048
#define NV 6
#define MOMENT_F 1.6384f          // N/10000
#define SEGS 512
#define RPS (NR / SEGS)           // 32 rows per segment
#define NCHUNK 8
#define SEG_PER_CHUNK (SEGS / NCHUNK)  // 64

// part : SEGS*NV slabs of 1024 float4: [512 sum][512 sq]  (48 MB)
// part2: NCHUNK*NV slabs, same layout (786 KB). All fully overwritten.

// ---------------------------------------------------------------------------
// K1: 512 blocks x 512 thr. Block s streams rows r0..r0+31 SEQUENTIALLY
// (contiguous 256 KB), 8 unconditional named float4 loads per group ->
// 8 dwordx4 in flight. Row's view is block-uniform: readfirstlane + scalar
// branch chain selects one of 6 register accumulator pairs (no divergence).
// ---------------------------------------------------------------------------
__global__ __launch_bounds__(512, 4) void k1_segstats(
    const float* __restrict__ x, const int* __restrict__ views,
    float4* __restrict__ part4) {
  const int s = blockIdx.x;
  const int t = threadIdx.x;
  const int r0 = s * RPS;

  __shared__ int vlds[RPS];
  if (t < RPS) vlds[t] = views[r0 + t];
  __syncthreads();

  float4 sm[NV], sq[NV];
#pragma unroll
  for (int v = 0; v < NV; ++v) {
    sm[v] = make_float4(0.f, 0.f, 0.f, 0.f);
    sq[v] = make_float4(0.f, 0.f, 0.f, 0.f);
  }

  const float4* xp = (const float4*)x + (size_t)r0 * 512 + t;

#define ACC(v, b) \
  sm[v].x += b.x; sm[v].y += b.y; sm[v].z += b.z; sm[v].w += b.w; \
  sq[v].x = fmaf(b.x, b.x, sq[v].x); sq[v].y = fmaf(b.y, b.y, sq[v].y); \
  sq[v].z = fmaf(b.z, b.z, sq[v].z); sq[v].w = fmaf(b.w, b.w, sq[v].w);

#define CONSUME(b, ri) { \
  const int rv = __builtin_amdgcn_readfirstlane(vlds[rb + (ri)]); \
  if (rv == 0)      { ACC(0, b) } \
  else if (rv == 1) { ACC(1, b) } \
  else if (rv == 2) { ACC(2, b) } \
  else if (rv == 3) { ACC(3, b) } \
  else if (rv == 4) { ACC(4, b) } \
  else              { ACC(5, b) } }

#pragma unroll
  for (int rb = 0; rb < RPS; rb += 8) {
    float4 b0 = xp[(size_t)(rb + 0) * 512];
    float4 b1 = xp[(size_t)(rb + 1) * 512];
    float4 b2 = xp[(size_t)(rb + 2) * 512];
    float4 b3 = xp[(size_t)(rb + 3) * 512];
    float4 b4 = xp[(size_t)(rb + 4) * 512];
    float4 b5 = xp[(size_t)(rb + 5) * 512];
    float4 b6 = xp[(size_t)(rb + 6) * 512];
    float4 b7 = xp[(size_t)(rb + 7) * 512];
    CONSUME(b0, 0) CONSUME(b1, 1) CONSUME(b2, 2) CONSUME(b3, 3)
    CONSUME(b4, 4) CONSUME(b5, 5) CONSUME(b6, 6) CONSUME(b7, 7)
  }
#undef CONSUME
#undef ACC

#pragma unroll
  for (int v = 0; v < NV; ++v) {
    float4* slab = part4 + (size_t)(s * NV + v) * 1024;
    slab[t]       = sm[v];
    slab[512 + t] = sq[v];
  }
}

// ---------------------------------------------------------------------------
// K1b: reduce 512 segment slabs -> 8 chunk slabs. 192 blocks x 256 thr.
// Thread (chunk, v, slot) sums 64 float4 partials (unrolled -> ILP), plain
// store. part written just before -> L3-resident reads.
// ---------------------------------------------------------------------------
__global__ __launch_bounds__(256) void k1b_reduce(
    const float4* __restrict__ part4, float4* __restrict__ part24) {
  const int u = blockIdx.x * 256 + threadIdx.x;  // 0 .. 48*1024-1
  const int c4 = u & 1023;
  const int vv = u >> 10;        // ci*NV + v, 0..47
  const int ci = vv / NV;
  const int v  = vv - ci * NV;
  const int s0 = ci * SEG_PER_CHUNK;
  float4 acc = {0.f, 0.f, 0.f, 0.f};
#pragma unroll 8
  for (int i = 0; i < SEG_PER_CHUNK; ++i) {
    float4 p = part4[(size_t)((s0 + i) * NV + v) * 1024 + c4];
    acc.x += p.x; acc.y += p.y; acc.z += p.z; acc.w += p.w;
  }
  part24[(size_t)vv * 1024 + c4] = acc;
}

// ---------------------------------------------------------------------------
// K2: single block x 1024 thr. Counts from views (64 KB), finish chunk
// reduction + stats + loss (2 cols/thread), block reduce, plain-store out.
// ---------------------------------------------------------------------------
__global__ __launch_bounds__(1024) void k2_finish(
    const float* __restrict__ part2, const int* __restrict__ views,
    const float* __restrict__ cmean, const float* __restrict__ cstd,
    float* __restrict__ out) {
  const int t = threadIdx.x;
  const int lane = t & 63;
  const int w = t >> 6;

  float c6[NV] = {0.f, 0.f, 0.f, 0.f, 0.f, 0.f};
  const int4* v4 = (const int4*)views;
#pragma unroll
  for (int it = 0; it < NR / 4 / 1024; ++it) {
    int4 q = v4[t + it * 1024];
#pragma unroll
    for (int v = 0; v < NV; ++v)
      c6[v] += (float)((q.x == v) + (q.y == v) + (q.z == v) + (q.w == v));
  }
#pragma unroll
  for (int v = 0; v < NV; ++v)
    for (int o = 32; o > 0; o >>= 1) c6[v] += __shfl_down(c6[v], o, 64);
  __shared__ float lcnt[16][NV];
  __shared__ float cnt_s[NV];
  if (lane == 0)
#pragma unroll
    for (int v = 0; v < NV; ++v) lcnt[w][v] = c6[v];
  __syncthreads();
  if (t < NV) {
    float sc = 0.f;
#pragma unroll
    for (int i = 0; i < 16; ++i) sc += lcnt[i][t];
    cnt_s[t] = sc;
  }
  __syncthreads();

  float cnt[NV];
  float nvalid = 0.f;
#pragma unroll
  for (int v = 0; v < NV; ++v) {
    cnt[v] = cnt_s[v];
    nvalid += (cnt[v] > 1.5f) ? 1.f : 0.f;
  }

  float contrib = 0.f;
#pragma unroll
  for (int half = 0; half < 2; ++half) {
    const int c = t + half * 1024;
    float mean[NV], sd[NV];
    float nm = 0.f, ns = 0.f;
#pragma unroll
    for (int v = 0; v < NV; ++v) {
      float su = 0.f, sqv = 0.f;
#pragma unroll
      for (int ch = 0; ch < NCHUNK; ++ch) {
        const float* sl = part2 + (size_t)(ch * NV + v) * 4096;
        su  += sl[c];
        sqv += sl[2048 + c];
      }
      float n = fmaxf(cnt[v], 1.f);
      float mu = su / n;
      float var = (sqv - cnt[v] * mu * mu) / fmaxf(cnt[v] - 1.f, 1.f);
      float sdv = sqrtf(fmaxf(var, 0.f));
      mean[v] = mu;
      sd[v] = sdv;
      if (cnt[v] > 1.5f) { nm += mu; ns += sdv; }
    }
    nm /= nvalid;
    ns /= nvalid;
    const float cm = cmean[c] * (1.f - MOMENT_F) + nm * MOMENT_F;
    const float cs = cstd[c]  * (1.f - MOMENT_F) + ns * MOMENT_F;
#pragma unroll
    for (int v = 0; v < NV; ++v)
      if (cnt[v] > 1.5f) {
        float d1 = mean[v] - cm;
        float d2 = sd[v] - cs;
        contrib += d1 * d1 + d2 * d2;
      }
  }
  contrib /= (2.f * nvalid);

  for (int o = 32; o > 0; o >>= 1) contrib += __shfl_down(contrib, o, 64);
  __shared__ float wsum[16];
  if (lane == 0) wsum[w] = contrib;
  __syncthreads();
  if (t == 0) {
    float tot = 0.f;
#pragma unroll
    for (int i = 0; i < 16; ++i) tot += wsum[i];
    out[0] = tot;
  }
}

extern "C" void kernel_launch(void* const* d_in, const int* in_sizes, int n_in,
                              void* d_out, int out_size, void* d_ws, size_t ws_size,
                              hipStream_t stream) {
  const float* x     = (const float*)d_in[0];  // (N, C) f32
  const float* cmean = (const float*)d_in[1];  // (C,)  f32
  const float* cstd  = (const float*)d_in[2];  // (C,)  f32
  const int*   views = (const int*)d_in[3];    // (N,)  i32
  float* out = (float*)d_out;

  // ws: [part: SEGS*NV*4096 f = 48 MB][part2: NCHUNK*NV*4096 f = 786 KB]
  float* part  = (float*)d_ws;
  float* part2 = part + (size_t)SEGS * NV * 4096;

  k1_segstats<<<SEGS, 512, 0, stream>>>(x, views, (float4*)part);
  k1b_reduce<<<NCHUNK * NV * 1024 / 256, 256, 0, stream>>>(
      (const float4*)part, (float4*)part2);
  k2_finish<<<1, 1024, 0, stream>>>(part2, views, cmean, cstd, out);
}

// Round 5
// 212.996 us; speedup vs baseline: 1.0456x; 1.0456x over previous
//
#include <hip/hip_runtime.h>
#include <hip/hip_bf16.h>

#define NR 16384
#define CC 2048
#define NV 6
#define MOMENT_F 1.6384f          // N/10000
#define SEGS 256
#define RPS (NR / SEGS)           // 64 rows per segment == one wave of ballots

// part: SEGS*NV slabs of 1024 float4 : [512 sum][512 sq]  -> 25 MB
// cnt : SEGS*8 floats (per-segment per-view counts, stride 8 for alignment)

// ---------------------------------------------------------------------------
// K1: 256 blocks x 512 thr (8 waves/CU). Block s streams rows r0..r0+63
// SEQUENTIALLY (contiguous 512 KB), 8 unconditional named float4 loads per
// group (8 dwordx4 in flight). Row's view is block-uniform: readfirstlane +
// scalar branch chain selects one of 6 register accumulator pairs.
// Wave 0 computes per-segment per-view counts with ballots. Block 0 zeroes
// out (K2 atomicAdds into it; stream order makes this safe).
// ---------------------------------------------------------------------------
__global__ __launch_bounds__(512, 4) void k1_segstats(
    const float* __restrict__ x, const int* __restrict__ views,
    float4* __restrict__ part4, float* __restrict__ cnt,
    float* __restrict__ out) {
  const int s = blockIdx.x;
  const int t = threadIdx.x;
  const int r0 = s * RPS;

  __shared__ int vlds[RPS];
  if (t < RPS) vlds[t] = views[r0 + t];
  __syncthreads();

  if (t < 64) {                       // wave 0: per-view counts via ballot
    const int myv = vlds[t];
#pragma unroll
    for (int v = 0; v < NV; ++v) {
      unsigned long long m = __ballot(myv == v);
      if (t == v) cnt[s * 8 + v] = (float)__popcll(m);
    }
  }
  if (s == 0 && t == 0) out[0] = 0.f;

  float4 sm[NV], sq[NV];
#pragma unroll
  for (int v = 0; v < NV; ++v) {
    sm[v] = make_float4(0.f, 0.f, 0.f, 0.f);
    sq[v] = make_float4(0.f, 0.f, 0.f, 0.f);
  }

  const float4* xp = (const float4*)x + (size_t)r0 * 512 + t;

#define ACC(v, b) \
  sm[v].x += b.x; sm[v].y += b.y; sm[v].z += b.z; sm[v].w += b.w; \
  sq[v].x = fmaf(b.x, b.x, sq[v].x); sq[v].y = fmaf(b.y, b.y, sq[v].y); \
  sq[v].z = fmaf(b.z, b.z, sq[v].z); sq[v].w = fmaf(b.w, b.w, sq[v].w);

#define CONSUME(b, ri) { \
  const int rv = __builtin_amdgcn_readfirstlane(vlds[rb + (ri)]); \
  if (rv == 0)      { ACC(0, b) } \
  else if (rv == 1) { ACC(1, b) } \
  else if (rv == 2) { ACC(2, b) } \
  else if (rv == 3) { ACC(3, b) } \
  else if (rv == 4) { ACC(4, b) } \
  else              { ACC(5, b) } }

  for (int rb = 0; rb < RPS; rb += 8) {
    float4 b0 = xp[(size_t)(rb + 0) * 512];
    float4 b1 = xp[(size_t)(rb + 1) * 512];
    float4 b2 = xp[(size_t)(rb + 2) * 512];
    float4 b3 = xp[(size_t)(rb + 3) * 512];
    float4 b4 = xp[(size_t)(rb + 4) * 512];
    float4 b5 = xp[(size_t)(rb + 5) * 512];
    float4 b6 = xp[(size_t)(rb + 6) * 512];
    float4 b7 = xp[(size_t)(rb + 7) * 512];
    CONSUME(b0, 0) CONSUME(b1, 1) CONSUME(b2, 2) CONSUME(b3, 3)
    CONSUME(b4, 4) CONSUME(b5, 5) CONSUME(b6, 6) CONSUME(b7, 7)
  }
#undef CONSUME
#undef ACC

#pragma unroll
  for (int v = 0; v < NV; ++v) {
    float4* slab = part4 + (size_t)(s * NV + v) * 1024;
    slab[t]       = sm[v];
    slab[512 + t] = sq[v];
  }
}

// ---------------------------------------------------------------------------
// K2: 64 blocks x 256 thr. Block owns 32 columns. Thread (g = t>>5 in 0..7,
// cl = t&31): partial su/sq for column c over segments g::8 (all 6 views),
// coalesced L3-resident reads. LDS-reduce over g; g==0 threads finish
// stats + per-column loss; shuffle-reduce 32 lanes; one atomicAdd per block.
// ---------------------------------------------------------------------------
__global__ __launch_bounds__(256) void k2_finish(
    const float* __restrict__ part, const float* __restrict__ cnt,
    const float* __restrict__ cmean, const float* __restrict__ cstd,
    float* __restrict__ out) {
  const int t = threadIdx.x;
  const int g = t >> 5;
  const int cl = t & 31;
  const int c = blockIdx.x * 32 + cl;

  // ---- total counts: thread t sums segment t's 6 counts, block-reduce ----
  float c6[NV];
#pragma unroll
  for (int v = 0; v < NV; ++v) c6[v] = cnt[t * 8 + v];
#pragma unroll
  for (int v = 0; v < NV; ++v)
    for (int o = 32; o > 0; o >>= 1) c6[v] += __shfl_down(c6[v], o, 64);
  __shared__ float lcnt[4][NV];
  __shared__ float cntS[NV];
  const int lane = t & 63, w = t >> 6;
  if (lane == 0)
#pragma unroll
    for (int v = 0; v < NV; ++v) lcnt[w][v] = c6[v];
  __syncthreads();
  if (t < NV) cntS[t] = lcnt[0][t] + lcnt[1][t] + lcnt[2][t] + lcnt[3][t];
  __syncthreads();

  // ---- partial column sums over this thread's 32 segments ----
  float su[NV], sq[NV];
#pragma unroll
  for (int v = 0; v < NV; ++v) { su[v] = 0.f; sq[v] = 0.f; }
  for (int si = g; si < SEGS; si += 8) {
    const float* slab = part + (size_t)si * NV * 4096;
#pragma unroll
    for (int v = 0; v < NV; ++v) {
      su[v] += slab[v * 4096 + c];
      sq[v] += slab[v * 4096 + 2048 + c];
    }
  }

  __shared__ float red[8][32][2 * NV];   // 12 KB
#pragma unroll
  for (int v = 0; v < NV; ++v) {
    red[g][cl][v] = su[v];
    red[g][cl][NV + v] = sq[v];
  }
  __syncthreads();

  if (g == 0) {
#pragma unroll
    for (int gg = 1; gg < 8; ++gg)
#pragma unroll
      for (int v = 0; v < NV; ++v) {
        su[v] += red[gg][cl][v];
        sq[v] += red[gg][cl][NV + v];
      }

    float nvalid = 0.f;
#pragma unroll
    for (int v = 0; v < NV; ++v) nvalid += (cntS[v] > 1.5f) ? 1.f : 0.f;

    float mean[NV], sd[NV], nm = 0.f, ns = 0.f;
#pragma unroll
    for (int v = 0; v < NV; ++v) {
      float n = fmaxf(cntS[v], 1.f);
      float mu = su[v] / n;
      float var = (sq[v] - cntS[v] * mu * mu) / fmaxf(cntS[v] - 1.f, 1.f);
      float sdv = sqrtf(fmaxf(var, 0.f));
      mean[v] = mu; sd[v] = sdv;
      if (cntS[v] > 1.5f) { nm += mu; ns += sdv; }
    }
    nm /= nvalid; ns /= nvalid;
    const float cm = cmean[c] * (1.f - MOMENT_F) + nm * MOMENT_F;
    const float cs = cstd[c]  * (1.f - MOMENT_F) + ns * MOMENT_F;

    float contrib = 0.f;
#pragma unroll
    for (int v = 0; v < NV; ++v)
      if (cntS[v] > 1.5f) {
        float d1 = mean[v] - cm;
        float d2 = sd[v] - cs;
        contrib += d1 * d1 + d2 * d2;
      }
    contrib /= (2.f * nvalid);

    for (int o = 16; o > 0; o >>= 1) contrib += __shfl_down(contrib, o, 32);
    if (cl == 0) atomicAdd(out, contrib);
  }
}

extern "C" void kernel_launch(void* const* d_in, const int* in_sizes, int n_in,
                              void* d_out, int out_size, void* d_ws, size_t ws_size,
                              hipStream_t stream) {
  const float* x     = (const float*)d_in[0];  // (N, C) f32
  const float* cmean = (const float*)d_in[1];  // (C,)  f32
  const float* cstd  = (const float*)d_in[2];  // (C,)  f32
  const int*   views = (const int*)d_in[3];    // (N,)  i32
  float* out = (float*)d_out;

  // ws: [part: SEGS*NV*4096 f = 25 MB][cnt: SEGS*8 f = 8 KB]
  float* part = (float*)d_ws;
  float* cnt  = part + (size_t)SEGS * NV * 4096;

  k1_segstats<<<SEGS, 512, 0, stream>>>(x, views, (float4*)part, cnt, out);
  k2_finish<<<CC / 32, 256, 0, stream>>>(part, cnt, cmean, cstd, out);
}